// Round 5
// baseline (199.301 us; speedup 1.0000x reference)
//
#include <hip/hip_runtime.h>
#include <math.h>

#define DIM     512
#define NNODES  10000
#define NEDGES  200000
#define MPAD    10112   // 79 * 128

using short8  = __attribute__((ext_vector_type(8))) short;
using floatx4 = __attribute__((ext_vector_type(4))) float;
using half8   = __attribute__((ext_vector_type(8))) _Float16;

__device__ inline unsigned short f32_to_bf16_rn(float x) {
    unsigned u = __float_as_uint(x);
    unsigned r = (u + 0x7FFF + ((u >> 16) & 1)) >> 16;
    return (unsigned short)r;
}
__device__ inline float bf16_to_f32(unsigned short h) {
    return __uint_as_float(((unsigned)h) << 16);
}

// ---------------------------------------------------------------------------
// Split Z -> Zhi, Zlo (bf16, [MPAD][512]) + Zh16 (fp16, [MPAD][512]).
// ---------------------------------------------------------------------------
__global__ __launch_bounds__(256) void split_z(const float* __restrict__ Z,
                                               unsigned short* __restrict__ Zhi,
                                               unsigned short* __restrict__ Zlo,
                                               unsigned short* __restrict__ Zh16) {
    const int base = (blockIdx.x * 256 + threadIdx.x) * 4;
    const int m = base >> 9;
    float4 v = make_float4(0.f, 0.f, 0.f, 0.f);
    if (m < NNODES) v = *(const float4*)(Z + base);
    float x[4] = {v.x, v.y, v.z, v.w};
    ushort4 hi, lo, h16;
    unsigned short* hp = (unsigned short*)&hi;
    unsigned short* lp = (unsigned short*)&lo;
    _Float16* fp = (_Float16*)&h16;
    #pragma unroll
    for (int i = 0; i < 4; ++i) {
        unsigned short h = f32_to_bf16_rn(x[i]);
        hp[i] = h;
        lp[i] = f32_to_bf16_rn(x[i] - bf16_to_f32(h));
        fp[i] = (_Float16)x[i];
    }
    *(ushort4*)(Zhi + base)  = hi;
    *(ushort4*)(Zlo + base)  = lo;
    *(ushort4*)(Zh16 + base) = h16;
}

// ---------------------------------------------------------------------------
// Split + transpose W (fp32 [k][n]) -> Wht, Wlt (bf16 [n][k]).
// ---------------------------------------------------------------------------
__global__ __launch_bounds__(256) void split_w(const float* __restrict__ W,
                                               unsigned short* __restrict__ Wht,
                                               unsigned short* __restrict__ Wlt) {
    const int t  = blockIdx.x * 256 + threadIdx.x;
    const int n  = t >> 7;
    const int k0 = (t & 127) * 4;
    ushort4 hi, lo;
    unsigned short* hp = (unsigned short*)&hi;
    unsigned short* lp = (unsigned short*)&lo;
    #pragma unroll
    for (int i = 0; i < 4; ++i) {
        float x = W[(size_t)(k0 + i) * DIM + n];
        unsigned short h = f32_to_bf16_rn(x);
        hp[i] = h;
        lp[i] = f32_to_bf16_rn(x - bf16_to_f32(h));
    }
    *(ushort4*)(Wht + (size_t)n * DIM + k0) = hi;
    *(ushort4*)(Wlt + (size_t)n * DIM + k0) = lo;
}

// ---------------------------------------------------------------------------
// MFMA GEMM v3: 128x64 tile, BK=64, double-buffered LDS, 1 barrier/step.
// Grid (79,8)=632 blocks (~2.5/CU). K = 3 segs * 512 = 24 steps of 64.
// LDS layout per buffer: A[kk][row][32k] 64B rows (m97-proven), B same.
// ---------------------------------------------------------------------------
__global__ __launch_bounds__(256) void gemm_mfma(const unsigned short* __restrict__ Zhi,
                                                 const unsigned short* __restrict__ Zlo,
                                                 const unsigned short* __restrict__ Wht,
                                                 const unsigned short* __restrict__ Wlt,
                                                 float* __restrict__ C) {
    __shared__ unsigned short ldsA[2 * 8192];  // 2 bufs * (2kk * 128row * 32k)
    __shared__ unsigned short ldsB[2 * 4096];  // 2 bufs * (2kk * 64row * 32k)

    const int t  = threadIdx.x;
    const int m0 = blockIdx.x * 128;
    const int n0 = blockIdx.y * 64;

    const int l  = t & 63;
    const int w  = t >> 6;
    const int wm = (w & 1) * 64;
    const int wn = (w >> 1) * 32;
    const int lm = l & 15;
    const int lq = l >> 4;

    const unsigned short* __restrict__ Asegs[3] = {Zhi, Zlo, Zhi};
    const unsigned short* __restrict__ Bsegs[3] = {Wht, Wht, Wlt};

    floatx4 acc[4][2] = {};

    const unsigned wave_base = (unsigned)(t & 192);

    // stage step `st` into buffer `buf`
    auto stage = [&](int buf, int st) {
        const int seg = st >> 3;
        const int k0  = (st & 7) * 64;
        const unsigned short* Ap = Asegs[seg] + (size_t)m0 * DIM;
        const unsigned short* Bp = Bsegs[seg] + (size_t)n0 * DIM;
        #pragma unroll
        for (int p = 0; p < 4; ++p) {
            const int s   = p * 256 + t;
            const int kk  = s >> 9;
            const int row = (s >> 2) & 127;
            const int ch  = s & 3;
            const unsigned short* src = Ap + (size_t)row * DIM + k0 + kk * 32 + ch * 8;
            __builtin_amdgcn_global_load_lds(
                (const __attribute__((address_space(1))) void*)src,
                (__attribute__((address_space(3))) void*)&ldsA[buf * 8192 + (p * 256 + wave_base) * 8],
                16, 0, 0);
        }
        #pragma unroll
        for (int p = 0; p < 2; ++p) {
            const int s   = p * 256 + t;
            const int kk  = s >> 8;
            const int row = (s >> 2) & 63;
            const int ch  = s & 3;
            const unsigned short* src = Bp + (size_t)row * DIM + k0 + kk * 32 + ch * 8;
            __builtin_amdgcn_global_load_lds(
                (const __attribute__((address_space(1))) void*)src,
                (__attribute__((address_space(3))) void*)&ldsB[buf * 4096 + (p * 256 + wave_base) * 8],
                16, 0, 0);
        }
    };

    stage(0, 0);
    __syncthreads();   // drain stage 0

    for (int s = 0; s < 24; ++s) {
        const int buf = s & 1;
        if (s < 23) stage(buf ^ 1, s + 1);   // prefetch: flies during compute below

        const unsigned short* A0 = &ldsA[buf * 8192];
        const unsigned short* B0 = &ldsB[buf * 4096];
        short8 aF[4][2], bF[2][2];
        #pragma unroll
        for (int kk = 0; kk < 2; ++kk) {
            #pragma unroll
            for (int i = 0; i < 4; ++i)
                aF[i][kk] = *(const short8*)&A0[kk * 4096 + (wm + 16 * i + lm) * 32 + lq * 8];
            #pragma unroll
            for (int j = 0; j < 2; ++j)
                bF[j][kk] = *(const short8*)&B0[kk * 2048 + (wn + 16 * j + lm) * 32 + lq * 8];
        }
        #pragma unroll
        for (int kk = 0; kk < 2; ++kk)
            #pragma unroll
            for (int i = 0; i < 4; ++i)
                #pragma unroll
                for (int j = 0; j < 2; ++j)
                    acc[i][j] = __builtin_amdgcn_mfma_f32_16x16x32_bf16(
                                    aF[i][kk], bF[j][kk], acc[i][j], 0, 0, 0);

        __syncthreads();   // drains prefetch (overlapped w/ compute) + WAR guard
    }

    #pragma unroll
    for (int i = 0; i < 4; ++i)
        #pragma unroll
        for (int j = 0; j < 2; ++j)
            #pragma unroll
            for (int r = 0; r < 4; ++r) {
                const int gm = m0 + wm + 16 * i + lq * 4 + r;
                const int gn = n0 + wn + 16 * j + lm;
                if (gm < NNODES)
                    C[(size_t)gm * DIM + gn] = acc[i][j][r];
            }
}

// ---------------------------------------------------------------------------
// fp32 GEMM fallback (ws too small for split scratch)
// ---------------------------------------------------------------------------
#define GTM 128
#define GTN 64
#define GTK 16
#define LDA 132
#define LDB 68

__global__ __launch_bounds__(256) void gemm_zw(const float* __restrict__ A,
                                               const float* __restrict__ B,
                                               float* __restrict__ C) {
    __shared__ float As[GTK * LDA];
    __shared__ float Bs[GTK * LDB];

    const int t  = threadIdx.x;
    const int m0 = blockIdx.x * GTM;
    const int n0 = blockIdx.y * GTN;
    const int tx = t & 15;
    const int ty = t >> 4;

    float acc[8][4] = {};

    for (int k0 = 0; k0 < DIM; k0 += GTK) {
        #pragma unroll
        for (int p = 0; p < 2; ++p) {
            int f  = t + p * 256;
            int mm = f >> 2;
            int kq = f & 3;
            int m  = m0 + mm;
            float4 v = make_float4(0.f, 0.f, 0.f, 0.f);
            if (m < NNODES)
                v = *(const float4*)(A + (size_t)m * DIM + k0 + kq * 4);
            As[(kq * 4 + 0) * LDA + mm] = v.x;
            As[(kq * 4 + 1) * LDA + mm] = v.y;
            As[(kq * 4 + 2) * LDA + mm] = v.z;
            As[(kq * 4 + 3) * LDA + mm] = v.w;
        }
        {
            int kb = t >> 4, n4 = t & 15;
            *(float4*)&Bs[kb * LDB + n4 * 4] =
                *(const float4*)(B + (size_t)(k0 + kb) * DIM + n0 + n4 * 4);
        }
        __syncthreads();

        #pragma unroll
        for (int kk = 0; kk < GTK; ++kk) {
            float4 a0 = *(const float4*)&As[kk * LDA + ty * 8];
            float4 a1 = *(const float4*)&As[kk * LDA + ty * 8 + 4];
            float4 b  = *(const float4*)&Bs[kk * LDB + tx * 4];
            float av[8] = {a0.x, a0.y, a0.z, a0.w, a1.x, a1.y, a1.z, a1.w};
            float bv[4] = {b.x, b.y, b.z, b.w};
            #pragma unroll
            for (int i = 0; i < 8; ++i)
                #pragma unroll
                for (int j = 0; j < 4; ++j)
                    acc[i][j] = fmaf(av[i], bv[j], acc[i][j]);
        }
        __syncthreads();
    }

    #pragma unroll
    for (int i = 0; i < 8; ++i) {
        int m = m0 + ty * 8 + i;
        if (m < NNODES)
            *(float4*)(C + (size_t)m * DIM + n0 + tx * 4) =
                make_float4(acc[i][0], acc[i][1], acc[i][2], acc[i][3]);
    }
}

// ---------------------------------------------------------------------------
// Counting sort of edges by row
// ---------------------------------------------------------------------------
__global__ void zero_counts(int* __restrict__ counts) {
    int i = blockIdx.x * blockDim.x + threadIdx.x;
    if (i < NNODES) counts[i] = 0;
}

__global__ void hist_rows(const int* __restrict__ eidx, int* __restrict__ counts) {
    int e = blockIdx.x * blockDim.x + threadIdx.x;
    if (e < NEDGES) atomicAdd(&counts[eidx[e]], 1);
}

__global__ __launch_bounds__(1024) void scan_counts(const int* __restrict__ counts,
                                                    int* __restrict__ offs,
                                                    int* __restrict__ cursor) {
    __shared__ int wsum[16];
    __shared__ int woff[17];
    const int t    = threadIdx.x;
    const int lane = t & 63;
    const int wv   = t >> 6;

    int local[10];
    int s = 0;
    if (t < 1000) {
        #pragma unroll
        for (int j = 0; j < 10; ++j) {
            local[j] = counts[t * 10 + j];
            s += local[j];
        }
    }
    int v = s;
    #pragma unroll
    for (int off = 1; off < 64; off <<= 1) {
        int u = __shfl_up(v, off, 64);
        if (lane >= off) v += u;
    }
    if (lane == 63) wsum[wv] = v;
    __syncthreads();
    if (t == 0) {
        int r = 0;
        #pragma unroll
        for (int i = 0; i < 16; ++i) { woff[i] = r; r += wsum[i]; }
        woff[16] = r;
    }
    __syncthreads();
    if (t < 1000) {
        int run = woff[wv] + (v - s);
        #pragma unroll
        for (int j = 0; j < 10; ++j) {
            offs[t * 10 + j]   = run;
            cursor[t * 10 + j] = run;
            run += local[j];
        }
    }
    if (t == 0) offs[NNODES] = woff[16];
}

__global__ void scatter_edges(const int* __restrict__ eidx,
                              int* __restrict__ cursor,
                              unsigned* __restrict__ keys) {
    int e = blockIdx.x * blockDim.x + threadIdx.x;
    if (e < NEDGES) {
        int r = eidx[e];
        int c = eidx[NEDGES + e];
        int pos = atomicAdd(&cursor[r], 1);
        keys[pos] = ((unsigned)c << 18) | (unsigned)e;
    }
}

// ---------------------------------------------------------------------------
// Edge scoring v3: one 64-lane wave per row bucket; ZW row in registers
// (no LDS, no barrier); Z gathered as fp16 (1 b128/lane/edge); 4-edge unroll.
// ---------------------------------------------------------------------------
__global__ __launch_bounds__(64) void edge_score_h(const float* __restrict__ ZW,
                                                   const _Float16* __restrict__ Zh,
                                                   const unsigned* __restrict__ keys,
                                                   const int* __restrict__ offs,
                                                   float* __restrict__ out) {
    const int r = blockIdx.x;
    const int start = offs[r];
    const int end   = offs[r + 1];
    if (start == end) return;

    const int lane = threadIdx.x;
    const float4 a0 = *(const float4*)(ZW + (size_t)r * DIM + lane * 8);
    const float4 a1 = *(const float4*)(ZW + (size_t)r * DIM + lane * 8 + 4);
    const float a[8] = {a0.x, a0.y, a0.z, a0.w, a1.x, a1.y, a1.z, a1.w};

    int i = start;
    for (; i + 3 < end; i += 4) {
        unsigned k0 = keys[i], k1 = keys[i + 1], k2 = keys[i + 2], k3 = keys[i + 3];
        half8 h0 = *(const half8*)(Zh + (size_t)(k0 >> 18) * DIM + lane * 8);
        half8 h1 = *(const half8*)(Zh + (size_t)(k1 >> 18) * DIM + lane * 8);
        half8 h2 = *(const half8*)(Zh + (size_t)(k2 >> 18) * DIM + lane * 8);
        half8 h3 = *(const half8*)(Zh + (size_t)(k3 >> 18) * DIM + lane * 8);

        float s0 = a[0] * (float)h0[0], s1 = a[0] * (float)h1[0];
        float s2 = a[0] * (float)h2[0], s3 = a[0] * (float)h3[0];
        #pragma unroll
        for (int j = 1; j < 8; ++j) {
            s0 = fmaf(a[j], (float)h0[j], s0);
            s1 = fmaf(a[j], (float)h1[j], s1);
            s2 = fmaf(a[j], (float)h2[j], s2);
            s3 = fmaf(a[j], (float)h3[j], s3);
        }
        #pragma unroll
        for (int off = 32; off > 0; off >>= 1) {
            s0 += __shfl_xor(s0, off, 64);
            s1 += __shfl_xor(s1, off, 64);
            s2 += __shfl_xor(s2, off, 64);
            s3 += __shfl_xor(s3, off, 64);
        }
        if (lane == 0) {
            out[k0 & 0x3FFFFu] = 1.0f / (1.0f + expf(-s0));
            out[k1 & 0x3FFFFu] = 1.0f / (1.0f + expf(-s1));
            out[k2 & 0x3FFFFu] = 1.0f / (1.0f + expf(-s2));
            out[k3 & 0x3FFFFu] = 1.0f / (1.0f + expf(-s3));
        }
    }
    for (; i < end; ++i) {
        unsigned k = keys[i];
        half8 h = *(const half8*)(Zh + (size_t)(k >> 18) * DIM + lane * 8);
        float s = a[0] * (float)h[0];
        #pragma unroll
        for (int j = 1; j < 8; ++j)
            s = fmaf(a[j], (float)h[j], s);
        #pragma unroll
        for (int off = 32; off > 0; off >>= 1)
            s += __shfl_xor(s, off, 64);
        if (lane == 0)
            out[k & 0x3FFFFu] = 1.0f / (1.0f + expf(-s));
    }
}

// ---------------------------------------------------------------------------
// Fallback edge scoring (unsorted, fp32)
// ---------------------------------------------------------------------------
__global__ __launch_bounds__(256) void edge_score(const float* __restrict__ ZW,
                                                  const float* __restrict__ Z,
                                                  const int* __restrict__ eidx,
                                                  float* __restrict__ out) {
    const int e    = blockIdx.x * 4 + (threadIdx.x >> 6);
    const int lane = threadIdx.x & 63;

    const int r = eidx[e];
    const int c = eidx[NEDGES + e];

    const float4* pr = (const float4*)(ZW + (size_t)r * DIM);
    const float4* pc = (const float4*)(Z  + (size_t)c * DIM);

    float4 a0 = pr[lane * 2 + 0];
    float4 a1 = pr[lane * 2 + 1];
    float4 b0 = pc[lane * 2 + 0];
    float4 b1 = pc[lane * 2 + 1];

    float s = a0.x * b0.x;
    s = fmaf(a0.y, b0.y, s);
    s = fmaf(a0.z, b0.z, s);
    s = fmaf(a0.w, b0.w, s);
    s = fmaf(a1.x, b1.x, s);
    s = fmaf(a1.y, b1.y, s);
    s = fmaf(a1.z, b1.z, s);
    s = fmaf(a1.w, b1.w, s);

    #pragma unroll
    for (int off = 32; off > 0; off >>= 1)
        s += __shfl_xor(s, off, 64);

    if (lane == 0)
        out[e] = 1.0f / (1.0f + expf(-s));
}

// ---------------------------------------------------------------------------
extern "C" void kernel_launch(void* const* d_in, const int* in_sizes, int n_in,
                              void* d_out, int out_size, void* d_ws, size_t ws_size,
                              hipStream_t stream) {
    const float* Z  = (const float*)d_in[0];
    const float* W  = (const float*)d_in[1];
    const int*   EI = (const int*)d_in[2];
    float* out = (float*)d_out;

    char* p = (char*)d_ws;
    float* ZW = (float*)p;                     p += (size_t)NNODES * DIM * 4;
    unsigned short* Zhi  = (unsigned short*)p; p += (size_t)MPAD * DIM * 2;
    unsigned short* Zlo  = (unsigned short*)p; p += (size_t)MPAD * DIM * 2;
    unsigned short* Wht  = (unsigned short*)p; p += (size_t)DIM * DIM * 2;
    unsigned short* Wlt  = (unsigned short*)p; p += (size_t)DIM * DIM * 2;
    unsigned short* Zh16 = (unsigned short*)p; p += (size_t)MPAD * DIM * 2;
    int* counts = (int*)p;                     p += (size_t)NNODES * 4;
    int* offs   = (int*)p;                     p += (size_t)(NNODES + 1) * 4;
    int* cursor = (int*)p;                     p += (size_t)NNODES * 4;
    unsigned* keys = (unsigned*)p;             p += (size_t)NEDGES * 4;
    const size_t need_full = (size_t)(p - (char*)d_ws);
    const size_t need_sort = (size_t)NNODES * DIM * 4 +
                             (size_t)(NNODES * 3 + 1) * 4 + (size_t)NEDGES * 4;

    const bool full = (ws_size >= need_full);

    if (full) {
        split_z<<<(MPAD * DIM / 4 + 255) / 256, 256, 0, stream>>>(Z, Zhi, Zlo, Zh16);
        split_w<<<(DIM * DIM / 4 + 255) / 256, 256, 0, stream>>>(W, Wht, Wlt);
        dim3 g(MPAD / 128, DIM / 64);   // (79, 8)
        gemm_mfma<<<g, 256, 0, stream>>>(Zhi, Zlo, Wht, Wlt, ZW);
    } else {
        dim3 g1((NNODES + GTM - 1) / GTM, DIM / GTN);
        gemm_zw<<<g1, 256, 0, stream>>>(Z, W, ZW);
    }

    if (ws_size >= need_sort) {
        int* counts2 = counts; int* offs2 = offs; int* cursor2 = cursor; unsigned* keys2 = keys;
        if (!full) {
            char* q = (char*)d_ws + (size_t)NNODES * DIM * 4;
            counts2 = (int*)q;  q += (size_t)NNODES * 4;
            offs2   = (int*)q;  q += (size_t)(NNODES + 1) * 4;
            cursor2 = (int*)q;  q += (size_t)NNODES * 4;
            keys2   = (unsigned*)q;
        }
        zero_counts<<<(NNODES + 255) / 256, 256, 0, stream>>>(counts2);
        hist_rows<<<(NEDGES + 255) / 256, 256, 0, stream>>>(EI, counts2);
        scan_counts<<<1, 1024, 0, stream>>>(counts2, offs2, cursor2);
        scatter_edges<<<(NEDGES + 255) / 256, 256, 0, stream>>>(EI, cursor2, keys2);
        if (full)
            edge_score_h<<<NNODES, 64, 0, stream>>>(ZW, (const _Float16*)Zh16, keys2, offs2, out);
        else {
            // no fp16 table: fall back to fp32 bucketed-by-unsorted kernel
            edge_score<<<NEDGES / 4, 256, 0, stream>>>(ZW, Z, EI, out);
        }
    } else {
        edge_score<<<NEDGES / 4, 256, 0, stream>>>(ZW, Z, EI, out);
    }
}

// Round 6
// 168.991 us; speedup vs baseline: 1.1794x; 1.1794x over previous
//
#include <hip/hip_runtime.h>
#include <math.h>

#define DIM     512
#define NNODES  10000
#define NEDGES  200000
#define MPAD    10112   // >= 157*64 = 10048
#define NMB     157     // m-groups of 64

using short8  = __attribute__((ext_vector_type(8))) short;
using floatx4 = __attribute__((ext_vector_type(4))) float;
using half8   = __attribute__((ext_vector_type(8))) _Float16;

__device__ inline unsigned short f32_to_bf16_rn(float x) {
    unsigned u = __float_as_uint(x);
    unsigned r = (u + 0x7FFF + ((u >> 16) & 1)) >> 16;
    return (unsigned short)r;
}
__device__ inline float bf16_to_f32(unsigned short h) {
    return __uint_as_float(((unsigned)h) << 16);
}

// ---------------------------------------------------------------------------
// split_w: W (fp32 [k][n]) -> Wht, Wlt (bf16 [n][k]); also zeroes counts.
// 65536 threads.
// ---------------------------------------------------------------------------
__global__ __launch_bounds__(256) void split_w(const float* __restrict__ W,
                                               unsigned short* __restrict__ Wht,
                                               unsigned short* __restrict__ Wlt,
                                               int* __restrict__ counts) {
    const int t = blockIdx.x * 256 + threadIdx.x;
    if (t < NNODES) counts[t] = 0;
    const int n  = t >> 7;
    const int k0 = (t & 127) * 4;
    ushort4 hi, lo;
    unsigned short* hp = (unsigned short*)&hi;
    unsigned short* lp = (unsigned short*)&lo;
    #pragma unroll
    for (int i = 0; i < 4; ++i) {
        float x = W[(size_t)(k0 + i) * DIM + n];
        unsigned short h = f32_to_bf16_rn(x);
        hp[i] = h;
        lp[i] = f32_to_bf16_rn(x - bf16_to_f32(h));
    }
    *(ushort4*)(Wht + (size_t)n * DIM + k0) = hi;
    *(ushort4*)(Wlt + (size_t)n * DIM + k0) = lo;
}

// ---------------------------------------------------------------------------
// GEMM v4: fused-split MFMA. Block = 64m x 256n, BK=32, 16 K-steps.
// A: fp32 Z loaded to regs, split to bf16 hi/lo, ds_write to padded LDS
//    (stride 40 shorts = 80B -> 2-way banks, free). One A read feeds
//    3 pairings: hi*hi + hi*lo + lo*hi.
// B: Wht/Wlt staged via global_load_lds (m97 64B-row pattern); 1MB total,
//    L2-resident.
// n_idx==0 blocks also emit the fp16 edge-gather table Zh16.
// Grid: 314 blocks (157 m-groups x 2 n-groups).
// ---------------------------------------------------------------------------
__global__ __launch_bounds__(256) void gemm_mfma(const float* __restrict__ Z,
                                                 const unsigned short* __restrict__ Wht,
                                                 const unsigned short* __restrict__ Wlt,
                                                 float* __restrict__ ZW,
                                                 _Float16* __restrict__ Zh16) {
    __shared__ unsigned short Ahi[64 * 40];
    __shared__ unsigned short Alo[64 * 40];
    __shared__ unsigned short Bhi[256 * 32];
    __shared__ unsigned short Blo[256 * 32];

    const int t     = threadIdx.x;
    const int bid   = blockIdx.x;
    const int n_idx = bid & 1;
    const int m0    = (bid >> 1) * 64;
    const int n0    = n_idx * 256;

    const int l  = t & 63;
    const int w  = t >> 6;
    const int wn = w * 64;      // wave's n-chunk
    const int lm = l & 15;
    const int lq = l >> 4;

    // A staging coords: thread covers 8 consecutive k of one row
    const int arow  = t >> 2;
    const int asub  = t & 3;
    const bool avalid = (m0 + arow) < NNODES;
    const float* Abase = Z + (size_t)(m0 + arow) * DIM + asub * 8;

    floatx4 acc[4][4] = {};

    auto stageB = [&](int k0) {
        #pragma unroll
        for (int p = 0; p < 4; ++p) {
            const int s   = p * 256 + t;
            const int row = s >> 2;
            const int ch  = s & 3;
            const unsigned short* srcH = Wht + (size_t)(n0 + row) * DIM + k0 + ch * 8;
            const unsigned short* srcL = Wlt + (size_t)(n0 + row) * DIM + k0 + ch * 8;
            __builtin_amdgcn_global_load_lds(
                (const __attribute__((address_space(1))) void*)srcH,
                (__attribute__((address_space(3))) void*)&Bhi[(p * 256 + (t & 192)) * 8],
                16, 0, 0);
            __builtin_amdgcn_global_load_lds(
                (const __attribute__((address_space(1))) void*)srcL,
                (__attribute__((address_space(3))) void*)&Blo[(p * 256 + (t & 192)) * 8],
                16, 0, 0);
        }
    };

    float4 a0r = make_float4(0.f, 0.f, 0.f, 0.f);
    float4 a1r = a0r;
    auto loadA = [&](int k0) {
        if (avalid) {
            a0r = *(const float4*)(Abase + k0);
            a1r = *(const float4*)(Abase + k0 + 4);
        } else {
            a0r = make_float4(0.f, 0.f, 0.f, 0.f);
            a1r = a0r;
        }
    };

    stageB(0);
    loadA(0);

    for (int s = 0; s < 16; ++s) {
        const int k0 = s * 32;

        // convert current A regs -> bf16 hi/lo, write to LDS (padded layout)
        {
            float x[8] = {a0r.x, a0r.y, a0r.z, a0r.w, a1r.x, a1r.y, a1r.z, a1r.w};
            short8 h8, l8;
            half8 f16;
            #pragma unroll
            for (int j = 0; j < 8; ++j) {
                unsigned short h = f32_to_bf16_rn(x[j]);
                h8[j] = (short)h;
                l8[j] = (short)f32_to_bf16_rn(x[j] - bf16_to_f32(h));
                f16[j] = (_Float16)x[j];
            }
            *(short8*)&Ahi[arow * 40 + asub * 8] = h8;
            *(short8*)&Alo[arow * 40 + asub * 8] = l8;
            if (n_idx == 0)   // emit fp16 edge table once (rows < MPAD, safe)
                *(half8*)(Zh16 + (size_t)(m0 + arow) * DIM + k0 + asub * 8) = f16;
        }

        __syncthreads();   // drain B glds + A ds_writes

        const int k0n = ((s + 1) & 15) * 32;
        loadA(k0n);        // register prefetch: flies during MFMA phase

        short8 aH[4], aL[4], bH[4], bL[4];
        #pragma unroll
        for (int i = 0; i < 4; ++i) {
            aH[i] = *(const short8*)&Ahi[(16 * i + lm) * 40 + lq * 8];
            aL[i] = *(const short8*)&Alo[(16 * i + lm) * 40 + lq * 8];
        }
        #pragma unroll
        for (int j = 0; j < 4; ++j) {
            bH[j] = *(const short8*)&Bhi[(wn + 16 * j + lm) * 32 + lq * 8];
            bL[j] = *(const short8*)&Blo[(wn + 16 * j + lm) * 32 + lq * 8];
        }
        #pragma unroll
        for (int i = 0; i < 4; ++i)
            #pragma unroll
            for (int j = 0; j < 4; ++j)
                acc[i][j] = __builtin_amdgcn_mfma_f32_16x16x32_bf16(aH[i], bH[j], acc[i][j], 0, 0, 0);
        #pragma unroll
        for (int i = 0; i < 4; ++i)
            #pragma unroll
            for (int j = 0; j < 4; ++j)
                acc[i][j] = __builtin_amdgcn_mfma_f32_16x16x32_bf16(aH[i], bL[j], acc[i][j], 0, 0, 0);
        #pragma unroll
        for (int i = 0; i < 4; ++i)
            #pragma unroll
            for (int j = 0; j < 4; ++j)
                acc[i][j] = __builtin_amdgcn_mfma_f32_16x16x32_bf16(aL[i], bH[j], acc[i][j], 0, 0, 0);

        __syncthreads();   // WAR guard before next stage/ds_write
        if (s < 15) stageB(k0n);
    }

    #pragma unroll
    for (int i = 0; i < 4; ++i)
        #pragma unroll
        for (int j = 0; j < 4; ++j)
            #pragma unroll
            for (int r = 0; r < 4; ++r) {
                const int gm = m0 + 16 * i + lq * 4 + r;
                const int gn = n0 + wn + 16 * j + lm;
                if (gm < NNODES)
                    ZW[(size_t)gm * DIM + gn] = acc[i][j][r];
            }
}

// ---------------------------------------------------------------------------
// fp32 GEMM fallback (ws too small)
// ---------------------------------------------------------------------------
#define GTM 128
#define GTN 64
#define GTK 16
#define LDA 132
#define LDB 68

__global__ __launch_bounds__(256) void gemm_zw(const float* __restrict__ A,
                                               const float* __restrict__ B,
                                               float* __restrict__ C) {
    __shared__ float As[GTK * LDA];
    __shared__ float Bs[GTK * LDB];

    const int t  = threadIdx.x;
    const int m0 = blockIdx.x * GTM;
    const int n0 = blockIdx.y * GTN;
    const int tx = t & 15;
    const int ty = t >> 4;

    float acc[8][4] = {};

    for (int k0 = 0; k0 < DIM; k0 += GTK) {
        #pragma unroll
        for (int p = 0; p < 2; ++p) {
            int f  = t + p * 256;
            int mm = f >> 2;
            int kq = f & 3;
            int m  = m0 + mm;
            float4 v = make_float4(0.f, 0.f, 0.f, 0.f);
            if (m < NNODES)
                v = *(const float4*)(A + (size_t)m * DIM + k0 + kq * 4);
            As[(kq * 4 + 0) * LDA + mm] = v.x;
            As[(kq * 4 + 1) * LDA + mm] = v.y;
            As[(kq * 4 + 2) * LDA + mm] = v.z;
            As[(kq * 4 + 3) * LDA + mm] = v.w;
        }
        {
            int kb = t >> 4, n4 = t & 15;
            *(float4*)&Bs[kb * LDB + n4 * 4] =
                *(const float4*)(B + (size_t)(k0 + kb) * DIM + n0 + n4 * 4);
        }
        __syncthreads();

        #pragma unroll
        for (int kk = 0; kk < GTK; ++kk) {
            float4 a0 = *(const float4*)&As[kk * LDA + ty * 8];
            float4 a1 = *(const float4*)&As[kk * LDA + ty * 8 + 4];
            float4 b  = *(const float4*)&Bs[kk * LDB + tx * 4];
            float av[8] = {a0.x, a0.y, a0.z, a0.w, a1.x, a1.y, a1.z, a1.w};
            float bv[4] = {b.x, b.y, b.z, b.w};
            #pragma unroll
            for (int i = 0; i < 8; ++i)
                #pragma unroll
                for (int j = 0; j < 4; ++j)
                    acc[i][j] = fmaf(av[i], bv[j], acc[i][j]);
        }
        __syncthreads();
    }

    #pragma unroll
    for (int i = 0; i < 8; ++i) {
        int m = m0 + ty * 8 + i;
        if (m < NNODES)
            *(float4*)(C + (size_t)m * DIM + n0 + tx * 4) =
                make_float4(acc[i][0], acc[i][1], acc[i][2], acc[i][3]);
    }
}

// ---------------------------------------------------------------------------
// Counting sort of edges by row
// ---------------------------------------------------------------------------
__global__ void hist_rows(const int* __restrict__ eidx, int* __restrict__ counts) {
    int e = blockIdx.x * blockDim.x + threadIdx.x;
    if (e < NEDGES) atomicAdd(&counts[eidx[e]], 1);
}

__global__ __launch_bounds__(1024) void scan_counts(const int* __restrict__ counts,
                                                    int* __restrict__ offs,
                                                    int* __restrict__ cursor) {
    __shared__ int wsum[16];
    __shared__ int woff[17];
    const int t    = threadIdx.x;
    const int lane = t & 63;
    const int wv   = t >> 6;

    int local[10];
    int s = 0;
    if (t < 1000) {
        #pragma unroll
        for (int j = 0; j < 10; ++j) {
            local[j] = counts[t * 10 + j];
            s += local[j];
        }
    }
    int v = s;
    #pragma unroll
    for (int off = 1; off < 64; off <<= 1) {
        int u = __shfl_up(v, off, 64);
        if (lane >= off) v += u;
    }
    if (lane == 63) wsum[wv] = v;
    __syncthreads();
    if (t == 0) {
        int r = 0;
        #pragma unroll
        for (int i = 0; i < 16; ++i) { woff[i] = r; r += wsum[i]; }
        woff[16] = r;
    }
    __syncthreads();
    if (t < 1000) {
        int run = woff[wv] + (v - s);
        #pragma unroll
        for (int j = 0; j < 10; ++j) {
            offs[t * 10 + j]   = run;
            cursor[t * 10 + j] = run;
            run += local[j];
        }
    }
    if (t == 0) offs[NNODES] = woff[16];
}

__global__ void scatter_edges(const int* __restrict__ eidx,
                              int* __restrict__ cursor,
                              unsigned* __restrict__ keys) {
    int e = blockIdx.x * blockDim.x + threadIdx.x;
    if (e < NEDGES) {
        int r = eidx[e];
        int c = eidx[NEDGES + e];
        int pos = atomicAdd(&cursor[r], 1);
        keys[pos] = ((unsigned)c << 18) | (unsigned)e;
    }
}

// ---------------------------------------------------------------------------
// Edge scoring: one wave per row bucket; ZW row in regs; fp16 col gather.
// ---------------------------------------------------------------------------
__global__ __launch_bounds__(64) void edge_score_h(const float* __restrict__ ZW,
                                                   const _Float16* __restrict__ Zh,
                                                   const unsigned* __restrict__ keys,
                                                   const int* __restrict__ offs,
                                                   float* __restrict__ out) {
    const int r = blockIdx.x;
    const int start = offs[r];
    const int end   = offs[r + 1];
    if (start == end) return;

    const int lane = threadIdx.x;
    const float4 a0 = *(const float4*)(ZW + (size_t)r * DIM + lane * 8);
    const float4 a1 = *(const float4*)(ZW + (size_t)r * DIM + lane * 8 + 4);
    const float a[8] = {a0.x, a0.y, a0.z, a0.w, a1.x, a1.y, a1.z, a1.w};

    int i = start;
    for (; i + 3 < end; i += 4) {
        unsigned k0 = keys[i], k1 = keys[i + 1], k2 = keys[i + 2], k3 = keys[i + 3];
        half8 h0 = *(const half8*)(Zh + (size_t)(k0 >> 18) * DIM + lane * 8);
        half8 h1 = *(const half8*)(Zh + (size_t)(k1 >> 18) * DIM + lane * 8);
        half8 h2 = *(const half8*)(Zh + (size_t)(k2 >> 18) * DIM + lane * 8);
        half8 h3 = *(const half8*)(Zh + (size_t)(k3 >> 18) * DIM + lane * 8);

        float s0 = a[0] * (float)h0[0], s1 = a[0] * (float)h1[0];
        float s2 = a[0] * (float)h2[0], s3 = a[0] * (float)h3[0];
        #pragma unroll
        for (int j = 1; j < 8; ++j) {
            s0 = fmaf(a[j], (float)h0[j], s0);
            s1 = fmaf(a[j], (float)h1[j], s1);
            s2 = fmaf(a[j], (float)h2[j], s2);
            s3 = fmaf(a[j], (float)h3[j], s3);
        }
        #pragma unroll
        for (int off = 32; off > 0; off >>= 1) {
            s0 += __shfl_xor(s0, off, 64);
            s1 += __shfl_xor(s1, off, 64);
            s2 += __shfl_xor(s2, off, 64);
            s3 += __shfl_xor(s3, off, 64);
        }
        if (lane == 0) {
            out[k0 & 0x3FFFFu] = 1.0f / (1.0f + expf(-s0));
            out[k1 & 0x3FFFFu] = 1.0f / (1.0f + expf(-s1));
            out[k2 & 0x3FFFFu] = 1.0f / (1.0f + expf(-s2));
            out[k3 & 0x3FFFFu] = 1.0f / (1.0f + expf(-s3));
        }
    }
    for (; i < end; ++i) {
        unsigned k = keys[i];
        half8 h = *(const half8*)(Zh + (size_t)(k >> 18) * DIM + lane * 8);
        float s = a[0] * (float)h[0];
        #pragma unroll
        for (int j = 1; j < 8; ++j)
            s = fmaf(a[j], (float)h[j], s);
        #pragma unroll
        for (int off = 32; off > 0; off >>= 1)
            s += __shfl_xor(s, off, 64);
        if (lane == 0)
            out[k & 0x3FFFFu] = 1.0f / (1.0f + expf(-s));
    }
}

// ---------------------------------------------------------------------------
// Fallback edge scoring (unsorted, fp32)
// ---------------------------------------------------------------------------
__global__ __launch_bounds__(256) void edge_score(const float* __restrict__ ZW,
                                                  const float* __restrict__ Z,
                                                  const int* __restrict__ eidx,
                                                  float* __restrict__ out) {
    const int e    = blockIdx.x * 4 + (threadIdx.x >> 6);
    const int lane = threadIdx.x & 63;

    const int r = eidx[e];
    const int c = eidx[NEDGES + e];

    const float4* pr = (const float4*)(ZW + (size_t)r * DIM);
    const float4* pc = (const float4*)(Z  + (size_t)c * DIM);

    float4 a0 = pr[lane * 2 + 0];
    float4 a1 = pr[lane * 2 + 1];
    float4 b0 = pc[lane * 2 + 0];
    float4 b1 = pc[lane * 2 + 1];

    float s = a0.x * b0.x;
    s = fmaf(a0.y, b0.y, s);
    s = fmaf(a0.z, b0.z, s);
    s = fmaf(a0.w, b0.w, s);
    s = fmaf(a1.x, b1.x, s);
    s = fmaf(a1.y, b1.y, s);
    s = fmaf(a1.z, b1.z, s);
    s = fmaf(a1.w, b1.w, s);

    #pragma unroll
    for (int off = 32; off > 0; off >>= 1)
        s += __shfl_xor(s, off, 64);

    if (lane == 0)
        out[e] = 1.0f / (1.0f + expf(-s));
}

// ---------------------------------------------------------------------------
extern "C" void kernel_launch(void* const* d_in, const int* in_sizes, int n_in,
                              void* d_out, int out_size, void* d_ws, size_t ws_size,
                              hipStream_t stream) {
    const float* Z  = (const float*)d_in[0];
    const float* W  = (const float*)d_in[1];
    const int*   EI = (const int*)d_in[2];
    float* out = (float*)d_out;

    char* p = (char*)d_ws;
    float* ZW = (float*)p;                     p += (size_t)NNODES * DIM * 4;
    _Float16* Zh16 = (_Float16*)p;             p += (size_t)MPAD * DIM * 2;
    unsigned short* Wht = (unsigned short*)p;  p += (size_t)DIM * DIM * 2;
    unsigned short* Wlt = (unsigned short*)p;  p += (size_t)DIM * DIM * 2;
    int* counts = (int*)p;                     p += (size_t)NNODES * 4;
    int* offs   = (int*)p;                     p += (size_t)(NNODES + 1) * 4;
    int* cursor = (int*)p;                     p += (size_t)NNODES * 4;
    unsigned* keys = (unsigned*)p;             p += (size_t)NEDGES * 4;
    const size_t need_full = (size_t)(p - (char*)d_ws);

    if (ws_size >= need_full) {
        split_w<<<256, 256, 0, stream>>>(W, Wht, Wlt, counts);           // + zero counts
        gemm_mfma<<<NMB * 2, 256, 0, stream>>>(Z, Wht, Wlt, ZW, Zh16);   // + emit Zh16
        hist_rows<<<(NEDGES + 255) / 256, 256, 0, stream>>>(EI, counts);
        scan_counts<<<1, 1024, 0, stream>>>(counts, offs, cursor);
        scatter_edges<<<(NEDGES + 255) / 256, 256, 0, stream>>>(EI, cursor, keys);
        edge_score_h<<<NNODES, 64, 0, stream>>>(ZW, Zh16, keys, offs, out);
    } else {
        dim3 g1((NNODES + GTM - 1) / GTM, DIM / GTN);
        gemm_zw<<<g1, 256, 0, stream>>>(Z, W, ZW);
        edge_score<<<NEDGES / 4, 256, 0, stream>>>(ZW, Z, EI, out);
    }
}